// Round 6
// baseline (143.465 us; speedup 1.0000x reference)
//
#include <hip/hip_runtime.h>
#include <math.h>

#define N_SAMPLES 131072
#define HIDDEN    256
#define M_GRID    2048
#define REC       148          // floats per table record
#define U_LO      (-8.0f)
#define DELTA     0.0078125f   // 16 / 2048
#define INV_DELTA 128.0f

// Record layout (148 floats = 37 float4):
//   [0..16]   cw  (knot x positions, cw[0]=-5, cw[16]=5)
//   [17..19]  pad
//   for k in 0..15: base = 20 + 8k:
//     [base+0] ch[k]  [base+1] ch[k+1]  [base+2] dv[k]  [base+3] dv[k+1]
//     [base+4] lam[k] [base+5..7] pad
__device__ float g_H2[HIDDEN * M_GRID];     // 2 MB, layout [o][m]
__device__ float g_table[M_GRID * REC];     // 1.2 MB
__device__ float g_knots0[REC];
__device__ float g_P[HIDDEN * HIDDEN];      // P[k][o] = W2[o][k]*w1_k
__device__ float g_Q[HIDDEN * HIDDEN];      // Q[k][o] = W2[o][k]*b1_k
__device__ float g_ku[HIDDEN];              // sorted kink positions
__device__ int   g_kp[HIDDEN];              // payload: (k<<1) | (w1<0)

__device__ __forceinline__ float rcpf(float x) { return __builtin_amdgcn_rcpf(x); }

__device__ __forceinline__ float softplusf(float x) {
  return fmaxf(x, 0.0f) + log1pf(expf(-fabsf(x)));
}

// Process one 63-value raw-param column into a record (vectorized stores).
__device__ void process_column(const float* __restrict__ raw, int stride,
                               float* __restrict__ rec) {
  float v[16];
  float cw[17], ch[17], dv[17], lm[16];
  float mx = -1e30f;
#pragma unroll
  for (int k = 0; k < 16; k++) { v[k] = raw[k * stride]; mx = fmaxf(mx, v[k]); }
  float s = 0.0f;
#pragma unroll
  for (int k = 0; k < 16; k++) { v[k] = expf(v[k] - mx); s += v[k]; }
  float scl = 0.984f / s;  // (1 - MIN_BIN*K)
  cw[0] = -5.0f;
  float a = 0.0f;
#pragma unroll
  for (int k = 0; k < 16; k++) {
    a += fmaf(v[k], scl, 0.001f);
    cw[k + 1] = fmaf(a, 10.0f, -5.0f);
  }
  cw[16] = 5.0f;
  mx = -1e30f;
#pragma unroll
  for (int k = 0; k < 16; k++) { v[k] = raw[(16 + k) * stride]; mx = fmaxf(mx, v[k]); }
  s = 0.0f;
#pragma unroll
  for (int k = 0; k < 16; k++) { v[k] = expf(v[k] - mx); s += v[k]; }
  scl = 0.984f / s;
  ch[0] = -5.0f;
  a = 0.0f;
#pragma unroll
  for (int k = 0; k < 16; k++) {
    a += fmaf(v[k], scl, 0.001f);
    ch[k + 1] = fmaf(a, 10.0f, -5.0f);
  }
  ch[16] = 5.0f;
  dv[0] = 1.0f; dv[16] = 1.0f;
#pragma unroll
  for (int j = 0; j < 15; j++) dv[j + 1] = 0.001f + softplusf(raw[(32 + j) * stride]);
#pragma unroll
  for (int k = 0; k < 16; k++) {
    float xx = raw[(47 + k) * stride];
    lm[k] = fmaf(0.95f, 1.0f / (1.0f + expf(-xx)), 0.025f);
  }
  float4* r4 = (float4*)rec;
  r4[0] = make_float4(cw[0], cw[1], cw[2], cw[3]);
  r4[1] = make_float4(cw[4], cw[5], cw[6], cw[7]);
  r4[2] = make_float4(cw[8], cw[9], cw[10], cw[11]);
  r4[3] = make_float4(cw[12], cw[13], cw[14], cw[15]);
  r4[4] = make_float4(cw[16], 0.0f, 0.0f, 0.0f);
#pragma unroll
  for (int k = 0; k < 16; k++) {
    r4[5 + 2 * k] = make_float4(ch[k], ch[k + 1], dv[k], dv[k + 1]);
    r4[6 + 2 * k] = make_float4(lm[k], 0.0f, 0.0f, 0.0f);
  }
}

// Monotonic linear-rational spline (approx rcp/sqrt; tol 0.099 >> 1ulp).
__device__ __forceinline__ float spline_eval(float z, float xk, float xk1,
                                             float yk, float yk1,
                                             float dk, float dk1, float lam) {
  float xc = fminf(fmaxf(z, -5.0f), 5.0f);
  float wk = xk1 - xk;
  float hk = yk1 - yk;
  float wb = __builtin_amdgcn_sqrtf(dk * rcpf(dk1));
  float wc = fmaf(lam, dk, (1.0f - lam) * wb * dk1) * wk * rcpf(hk);
  float ya = yk;
  float yb = yk + hk;
  float yc = fmaf(lam * wb, yb, (1.0f - lam) * ya) * rcpf(fmaf(lam, wb, 1.0f - lam));
  float th = (xc - xk) * rcpf(wk);
  bool left = th <= lam;
  float num = left ? fmaf(ya, lam - th, wc * yc * th)
                   : fmaf(wc * yc, 1.0f - th, wb * yb * (th - lam));
  float den = left ? fmaf(wc, th, lam - th)
                   : fmaf(wc, 1.0f - th, wb * (th - lam));
  float y = num * rcpf(den);
  bool inside = (z >= -5.0f) && (z <= 5.0f);
  return inside ? y : z;
}

// ---- k_trans: build P[k][o] = W2[o][k]*w1_k, Q[k][o] = W2[o][k]*b1_k.
// Grid 16 blocks (4 o-tiles x 4 k-tiles), 256 threads, LDS 64x64 transpose.
__global__ __launch_bounds__(256) void k_trans(const float* __restrict__ W1,
                                               const float* __restrict__ b1,
                                               const float* __restrict__ W2) {
  __shared__ float L[64][65];  // [k_local][o_local]
  const int ot = blockIdx.x >> 2, kt = blockIdx.x & 3;
  const int t = threadIdx.x;
  {
    const int kl = t & 63, og = t >> 6;  // lanes contiguous in k -> coalesced
#pragma unroll
    for (int r = 0; r < 16; r++) {
      const int os = og * 16 + r;
      L[kl][os] = W2[(size_t)(ot * 64 + os) * 256 + kt * 64 + kl];
    }
  }
  __syncthreads();
  {
    const int ol = t & 63, kg = t >> 6;  // lanes contiguous in o -> coalesced
#pragma unroll
    for (int r = 0; r < 16; r++) {
      const int kl = kg * 16 + r;
      const int k = kt * 64 + kl;
      const float w1v = W1[2 * k];   // uniform
      const float b1v = b1[k];       // uniform
      const float v = L[kl][ol];
      g_P[(size_t)k * 256 + ot * 64 + ol] = v * w1v;
      g_Q[(size_t)k * 256 + ot * 64 + ol] = v * b1v;
    }
  }
}

// ---- k_sort: kink positions u*_k = -b1/w1, bitonic sort ascending. 1 block.
__global__ __launch_bounds__(256) void k_sort(const float* __restrict__ W1,
                                              const float* __restrict__ b1) {
  __shared__ float ku[256];
  __shared__ int   kp[256];
  const int t = threadIdx.x;
  {
    const float w1v = W1[2 * t];
    const float b1v = b1[t];
    ku[t] = (w1v == 0.0f) ? 3e38f : (-b1v / w1v);
    kp[t] = (t << 1) | (w1v < 0.0f ? 1 : 0);
  }
  for (int size = 2; size <= 256; size <<= 1) {
    for (int stride = size >> 1; stride > 0; stride >>= 1) {
      __syncthreads();
      const int partner = t ^ stride;
      if (partner > t) {
        const bool up = ((t & size) == 0);
        const float a = ku[t], b = ku[partner];
        if ((a > b) == up) {
          ku[t] = b; ku[partner] = a;
          const int tmp = kp[t]; kp[t] = kp[partner]; kp[partner] = tmp;
        }
      }
    }
  }
  __syncthreads();
  g_ku[t] = ku[t];
  g_kp[t] = kp[t];
}

// ---- k_h2: exact piecewise-linear sweep. H2[o][m] = relu(A*u + B + b2[o]).
// Grid 32 blocks (64-m tiles), 256 threads (thread = o). Uniform control flow.
__global__ __launch_bounds__(256) void k_h2(const float* __restrict__ W1,
                                            const float* __restrict__ b1,
                                            const float* __restrict__ b2) {
  __shared__ float ku[256];
  __shared__ int   kp[256];
  __shared__ float T[256][17];
  const int t = threadIdx.x;
  ku[t] = g_ku[t];
  kp[t] = g_kp[t];
  __syncthreads();
  const int m0 = blockIdx.x * 64;
  const float u0 = fmaf((float)m0, DELTA, U_LO);  // exact binary fraction
  // ---- init masked sums at u0 ----
  float A = 0.0f, B = 0.0f;
#pragma unroll 8
  for (int k = 0; k < 256; k++) {
    const float w1v = W1[2 * k];   // uniform
    const float b1v = b1[k];       // uniform
    const bool act = fmaf(w1v, u0, b1v) > 0.0f;
    const float p = g_P[(size_t)k * 256 + t];  // coalesced
    const float q = g_Q[(size_t)k * 256 + t];
    A += act ? p : 0.0f;
    B += act ? q : 0.0f;
  }
  // ---- first kink index with u* >= u0 (uniform binary search) ----
  int lo = 0, hi = 256;
  while (lo < hi) { const int mid = (lo + hi) >> 1; if (ku[mid] < u0) lo = mid + 1; else hi = mid; }
  int ptr = lo;
  const float b2o = b2[t];
  for (int j = 0; j < 64; j++) {
    const float u = fmaf((float)j, DELTA, u0);
    while (ptr < 256 && ku[ptr] <= u) {   // uniform loop
      const int pk = kp[ptr];
      const int kk = pk >> 1;
      const float sgn = (pk & 1) ? -1.0f : 1.0f;
      A = fmaf(sgn, g_P[(size_t)kk * 256 + t], A);
      B = fmaf(sgn, g_Q[(size_t)kk * 256 + t], B);
      ptr++;
    }
    T[t][j & 15] = fmaxf(fmaf(A, u, B) + b2o, 0.0f);
    if ((j & 15) == 15) {
      __syncthreads();
      const int mb = m0 + (j & ~15);
      const int oo = (t >> 4) * 16;
      const int mm = t & 15;
#pragma unroll
      for (int e = 0; e < 16; e++)
        g_H2[(size_t)(oo + e) * M_GRID + mb + mm] = T[oo + e][mm];
      __syncthreads();
    }
  }
}

// ---------------- Layer-3 GEMM (odd rows of W3) + param processing -> g_table
// (verbatim round-2 version)
__global__ __launch_bounds__(256) void k_gemm3proc(const float* __restrict__ W3,
                                                   const float* __restrict__ b3) {
  __shared__ float Wt[64][68];
  __shared__ float Ht[64][68];
  __shared__ float raws[64][65];  // [p][m]
  const int t = threadIdx.x;
  const int m0 = blockIdx.x * 64;
  const int ty = t >> 4, tx = t & 15;
  float acc[4][4] = {};
  for (int kc = 0; kc < 256; kc += 64) {
    {
      const int p = t >> 2, seg = t & 3;
      const int row = (p < 63) ? (2 * p + 1) : 1;
      const float* src = W3 + (size_t)row * 256 + kc + seg * 16;
#pragma unroll
      for (int q = 0; q < 4; q++) {
        float4 v = *(const float4*)(src + 4 * q);
        int k = seg * 16 + 4 * q;
        Wt[k + 0][p] = v.x; Wt[k + 1][p] = v.y;
        Wt[k + 2][p] = v.z; Wt[k + 3][p] = v.w;
      }
    }
    {
      const int k = t & 63, mseg = (t >> 6) * 16;
      const float* src = g_H2 + (size_t)(kc + k) * M_GRID + m0 + mseg;
#pragma unroll
      for (int q = 0; q < 4; q++) {
        float4 v = *(const float4*)(src + 4 * q);
        *(float4*)&Ht[k][mseg + 4 * q] = v;
      }
    }
    __syncthreads();
#pragma unroll
    for (int k = 0; k < 64; k++) {
      float4 av = *(const float4*)&Wt[k][ty * 4];
      float4 bv = *(const float4*)&Ht[k][tx * 4];
      acc[0][0] = fmaf(av.x, bv.x, acc[0][0]); acc[0][1] = fmaf(av.x, bv.y, acc[0][1]);
      acc[0][2] = fmaf(av.x, bv.z, acc[0][2]); acc[0][3] = fmaf(av.x, bv.w, acc[0][3]);
      acc[1][0] = fmaf(av.y, bv.x, acc[1][0]); acc[1][1] = fmaf(av.y, bv.y, acc[1][1]);
      acc[1][2] = fmaf(av.y, bv.z, acc[1][2]); acc[1][3] = fmaf(av.y, bv.w, acc[1][3]);
      acc[2][0] = fmaf(av.z, bv.x, acc[2][0]); acc[2][1] = fmaf(av.z, bv.y, acc[2][1]);
      acc[2][2] = fmaf(av.z, bv.z, acc[2][2]); acc[2][3] = fmaf(av.z, bv.w, acc[2][3]);
      acc[3][0] = fmaf(av.w, bv.x, acc[3][0]); acc[3][1] = fmaf(av.w, bv.y, acc[3][1]);
      acc[3][2] = fmaf(av.w, bv.z, acc[3][2]); acc[3][3] = fmaf(av.w, bv.w, acc[3][3]);
    }
    __syncthreads();
  }
#pragma unroll
  for (int ii = 0; ii < 4; ii++) {
    const int p = ty * 4 + ii;
    const int bi = (p < 63) ? (2 * p + 1) : 1;
    const float bias = b3[bi];
    raws[p][tx * 4 + 0] = acc[ii][0] + bias;
    raws[p][tx * 4 + 1] = acc[ii][1] + bias;
    raws[p][tx * 4 + 2] = acc[ii][2] + bias;
    raws[p][tx * 4 + 3] = acc[ii][3] + bias;
  }
  __syncthreads();
  if (t < 64)
    process_column(&raws[0][t], 65, g_table + (size_t)(m0 + t) * REC);
  if (t == 64 && blockIdx.x == 0)
    process_column(b3, 2, g_knots0);  // dim-0 constant knots
}

// ---------------- Main flow kernel: 4 steps per sample (verbatim round-2)
__global__ __launch_bounds__(256) void k_main(const float* __restrict__ x,
                                              float* __restrict__ out) {
  __shared__ float kn0[REC];
  for (int j = threadIdx.x; j < REC; j += 256) kn0[j] = g_knots0[j];
  __syncthreads();
  const int i = blockIdx.x * 256 + threadIdx.x;
  const float2 xv = ((const float2*)x)[i];
  float z0 = xv.x, z1 = xv.y;
  ((float2*)out)[i] = xv;  // step 0 = input
  for (int t = 0; t < 4; t++) {
    float tt = (z0 - U_LO) * INV_DELTA;
    int i0 = (int)floorf(tt);
    i0 = min(max(i0, 0), M_GRID - 2);
    float f = fminf(fmaxf(tt - (float)i0, 0.0f), 1.0f);
    const float* r0 = g_table + (size_t)i0 * REC;
    const float* r1 = r0 + REC;
    float cwv[17];
#pragma unroll
    for (int q = 0; q < 4; q++) {
      float4 a = *(const float4*)(r0 + 4 * q);
      float4 b = *(const float4*)(r1 + 4 * q);
      cwv[4 * q + 0] = fmaf(f, b.x - a.x, a.x);
      cwv[4 * q + 1] = fmaf(f, b.y - a.y, a.y);
      cwv[4 * q + 2] = fmaf(f, b.z - a.z, a.z);
      cwv[4 * q + 3] = fmaf(f, b.w - a.w, a.w);
    }
    cwv[16] = 5.0f;  // exact in every record
    float xc1 = fminf(fmaxf(z1, -5.0f), 5.0f);
    int k1 = -1;
    float xk = cwv[0], xk1 = cwv[16];
    bool seen = false;
#pragma unroll
    for (int j = 0; j < 16; j++) {
      bool c = xc1 >= cwv[j];
      k1 += c ? 1 : 0;
      xk = c ? cwv[j] : xk;
      bool ff = (!c) && (!seen);
      xk1 = ff ? cwv[j] : xk1;
      seen = seen || (!c);
    }
    const float* s0 = r0 + 20 + 8 * k1;
    const float* s1 = s0 + REC;
    float4 pa = *(const float4*)s0;
    float4 pb = *(const float4*)s1;
    float la = s0[4], lb = s1[4];
    float yk  = fmaf(f, pb.x - pa.x, pa.x);
    float yk1 = fmaf(f, pb.y - pa.y, pa.y);
    float dk  = fmaf(f, pb.z - pa.z, pa.z);
    float dk1 = fmaf(f, pb.w - pa.w, pa.w);
    float lam = fmaf(f, lb - la, la);
    float z1n = spline_eval(z1, xk, xk1, yk, yk1, dk, dk1, lam);
    float xc0 = fminf(fmaxf(z0, -5.0f), 5.0f);
    int k0 = -1;
    float xk0 = kn0[0], xk01 = kn0[16];
    bool seen0 = false;
#pragma unroll
    for (int j = 0; j < 16; j++) {
      float cj = kn0[j];
      bool c = xc0 >= cj;
      k0 += c ? 1 : 0;
      xk0 = c ? cj : xk0;
      bool ff = (!c) && (!seen0);
      xk01 = ff ? cj : xk01;
      seen0 = seen0 || (!c);
    }
    const int sb = 20 + 8 * k0;
    float z0n = spline_eval(z0, xk0, xk01, kn0[sb], kn0[sb + 1],
                            kn0[sb + 2], kn0[sb + 3], kn0[sb + 4]);
    z0 = z0n; z1 = z1n;
    ((float2*)(out + (size_t)(t + 1) * (N_SAMPLES * 2)))[i] = make_float2(z0, z1);
  }
}

extern "C" void kernel_launch(void* const* d_in, const int* in_sizes, int n_in,
                              void* d_out, int out_size, void* d_ws, size_t ws_size,
                              hipStream_t stream) {
  const float* x  = (const float*)d_in[0];
  const float* W1 = (const float*)d_in[1];
  const float* b1 = (const float*)d_in[2];
  const float* W2 = (const float*)d_in[3];
  const float* b2 = (const float*)d_in[4];
  const float* W3 = (const float*)d_in[5];
  const float* b3 = (const float*)d_in[6];
  float* out = (float*)d_out;
  hipLaunchKernelGGL(k_trans, dim3(16), dim3(256), 0, stream, W1, b1, W2);
  hipLaunchKernelGGL(k_sort, dim3(1), dim3(256), 0, stream, W1, b1);
  hipLaunchKernelGGL(k_h2, dim3(M_GRID / 64), dim3(256), 0, stream, W1, b1, b2);
  hipLaunchKernelGGL(k_gemm3proc, dim3(M_GRID / 64), dim3(256), 0, stream, W3, b3);
  hipLaunchKernelGGL(k_main, dim3(N_SAMPLES / 256), dim3(256), 0, stream, x, out);
}

// Round 7
// 127.684 us; speedup vs baseline: 1.1236x; 1.1236x over previous
//
#include <hip/hip_runtime.h>
#include <math.h>

#define N_SAMPLES 131072
#define HIDDEN    256
#define M_GRID    2048
#define REC       148          // floats per table record
#define U_LO      (-8.0f)
#define DELTA     0.0078125f   // 16 / 2048
#define INV_DELTA 128.0f

// Record layout (148 floats = 37 float4):
//   [0..16]   cw  (knot x positions, cw[0]=-5, cw[16]=5)
//   [17..19]  pad
//   for k in 0..15: base = 20 + 8k:
//     [base+0] ch[k]  [base+1] ch[k+1]  [base+2] dv[k]  [base+3] dv[k+1]
//     [base+4] lam[k] [base+5..7] pad
__device__ float  g_H2[HIDDEN * M_GRID];    // 2 MB, layout [k][m]
__device__ float  g_table[M_GRID * REC];    // 1.2 MB
__device__ float  g_knots0[REC];
__device__ float  g_W2T[HIDDEN * HIDDEN];   // [k][o]
__device__ float  g_W3T[HIDDEN * 64];       // [k][p] (odd rows of W3; p=63 dummy)
__device__ float2 g_W1P[HIDDEN];            // (w1_k, b1_k)
__device__ float  g_part[4 * 64 * M_GRID];  // k-split partials [s][p][m]

__device__ __forceinline__ float rcpf(float x) { return __builtin_amdgcn_rcpf(x); }

__device__ __forceinline__ float softplusf(float x) {
  return fmaxf(x, 0.0f) + log1pf(expf(-fabsf(x)));
}

// Process one 63-value raw-param column into a record (vectorized stores).
__device__ void process_column(const float* __restrict__ raw, int stride,
                               float* __restrict__ rec) {
  float v[16];
  float cw[17], ch[17], dv[17], lm[16];
  float mx = -1e30f;
#pragma unroll
  for (int k = 0; k < 16; k++) { v[k] = raw[k * stride]; mx = fmaxf(mx, v[k]); }
  float s = 0.0f;
#pragma unroll
  for (int k = 0; k < 16; k++) { v[k] = expf(v[k] - mx); s += v[k]; }
  float scl = 0.984f / s;  // (1 - MIN_BIN*K)
  cw[0] = -5.0f;
  float a = 0.0f;
#pragma unroll
  for (int k = 0; k < 16; k++) {
    a += fmaf(v[k], scl, 0.001f);
    cw[k + 1] = fmaf(a, 10.0f, -5.0f);
  }
  cw[16] = 5.0f;
  mx = -1e30f;
#pragma unroll
  for (int k = 0; k < 16; k++) { v[k] = raw[(16 + k) * stride]; mx = fmaxf(mx, v[k]); }
  s = 0.0f;
#pragma unroll
  for (int k = 0; k < 16; k++) { v[k] = expf(v[k] - mx); s += v[k]; }
  scl = 0.984f / s;
  ch[0] = -5.0f;
  a = 0.0f;
#pragma unroll
  for (int k = 0; k < 16; k++) {
    a += fmaf(v[k], scl, 0.001f);
    ch[k + 1] = fmaf(a, 10.0f, -5.0f);
  }
  ch[16] = 5.0f;
  dv[0] = 1.0f; dv[16] = 1.0f;
#pragma unroll
  for (int j = 0; j < 15; j++) dv[j + 1] = 0.001f + softplusf(raw[(32 + j) * stride]);
#pragma unroll
  for (int k = 0; k < 16; k++) {
    float xx = raw[(47 + k) * stride];
    lm[k] = fmaf(0.95f, 1.0f / (1.0f + expf(-xx)), 0.025f);
  }
  float4* r4 = (float4*)rec;
  r4[0] = make_float4(cw[0], cw[1], cw[2], cw[3]);
  r4[1] = make_float4(cw[4], cw[5], cw[6], cw[7]);
  r4[2] = make_float4(cw[8], cw[9], cw[10], cw[11]);
  r4[3] = make_float4(cw[12], cw[13], cw[14], cw[15]);
  r4[4] = make_float4(cw[16], 0.0f, 0.0f, 0.0f);
#pragma unroll
  for (int k = 0; k < 16; k++) {
    r4[5 + 2 * k] = make_float4(ch[k], ch[k + 1], dv[k], dv[k + 1]);
    r4[6 + 2 * k] = make_float4(lm[k], 0.0f, 0.0f, 0.0f);
  }
}

// Monotonic linear-rational spline (approx rcp/sqrt; tol 0.099 >> 1ulp).
__device__ __forceinline__ float spline_eval(float z, float xk, float xk1,
                                             float yk, float yk1,
                                             float dk, float dk1, float lam) {
  float xc = fminf(fmaxf(z, -5.0f), 5.0f);
  float wk = xk1 - xk;
  float hk = yk1 - yk;
  float wb = __builtin_amdgcn_sqrtf(dk * rcpf(dk1));
  float wc = fmaf(lam, dk, (1.0f - lam) * wb * dk1) * wk * rcpf(hk);
  float ya = yk;
  float yb = yk + hk;
  float yc = fmaf(lam * wb, yb, (1.0f - lam) * ya) * rcpf(fmaf(lam, wb, 1.0f - lam));
  float th = (xc - xk) * rcpf(wk);
  bool left = th <= lam;
  float num = left ? fmaf(ya, lam - th, wc * yc * th)
                   : fmaf(wc * yc, 1.0f - th, wb * yb * (th - lam));
  float den = left ? fmaf(wc, th, lam - th)
                   : fmaf(wc, 1.0f - th, wb * (th - lam));
  float y = num * rcpf(den);
  bool inside = (z >= -5.0f) && (z <= 5.0f);
  return inside ? y : z;
}

// ---- k_prep: transposes. Blocks 0..15: W2T (64x64 tiles). Blocks 16..19:
// W3T (odd rows). Block 16 also packs W1P. Transpose pattern verified in r6.
__global__ __launch_bounds__(256) void k_prep(const float* __restrict__ W1,
                                              const float* __restrict__ b1,
                                              const float* __restrict__ W2,
                                              const float* __restrict__ W3) {
  __shared__ float L[64][65];
  const int t = threadIdx.x;
  const int bid = blockIdx.x;
  const int c = t & 63, g = t >> 6;
  if (bid < 16) {
    const int ot = bid >> 2, kt = bid & 3;
#pragma unroll
    for (int r = 0; r < 16; r++) {
      const int os = g * 16 + r;
      L[c][os] = W2[(size_t)(ot * 64 + os) * 256 + kt * 64 + c];  // c=k_local, coalesced
    }
    __syncthreads();
#pragma unroll
    for (int r = 0; r < 16; r++) {
      const int kl = g * 16 + r;
      g_W2T[(size_t)(kt * 64 + kl) * 256 + ot * 64 + c] = L[kl][c];  // c=o_local, coalesced
    }
  } else {
    const int kt = bid - 16;
#pragma unroll
    for (int r = 0; r < 16; r++) {
      const int ps = g * 16 + r;
      const int row = (ps < 63) ? (2 * ps + 1) : 1;  // p=63 dummy (never read downstream)
      L[c][ps] = W3[(size_t)row * 256 + kt * 64 + c];
    }
    __syncthreads();
#pragma unroll
    for (int r = 0; r < 16; r++) {
      const int kl = g * 16 + r;
      g_W3T[(size_t)(kt * 64 + kl) * 64 + c] = L[kl][c];
    }
    if (kt == 0) g_W1P[t] = make_float2(W1[2 * t], b1[t]);
  }
}

// ---- k_g2: H2[o][m] = relu(W2[o,:]·h(u_m) + b2[o]).
// Grid (32 m-tiles, 8 o-tiles) = 256 blocks (1/CU), 4 waves/block.
// lane = m; wave covers 8 o's. A via wave-uniform s_load from W2T;
// B = h_k(u) computed in-register (2 VALU); no LDS in the loop.
__global__ __launch_bounds__(256) void k_g2(const float* __restrict__ b2) {
  const int t = threadIdx.x;
  const int lane = t & 63;
  const int wave = t >> 6;
  const int m = blockIdx.x * 64 + lane;
  const int ob = blockIdx.y * 32 + wave * 8;
  const float u = fmaf((float)m, DELTA, U_LO);
  float acc[8] = {};
#pragma unroll 4
  for (int k = 0; k < 256; k++) {
    const float2 wp = g_W1P[k];                         // uniform -> s_load
    const float h = fmaxf(fmaf(u, wp.x, wp.y), 0.0f);
    const float4* a4 = (const float4*)(g_W2T + (size_t)k * 256 + ob);  // uniform
    const float4 a0 = a4[0], a1 = a4[1];
    acc[0] = fmaf(a0.x, h, acc[0]); acc[1] = fmaf(a0.y, h, acc[1]);
    acc[2] = fmaf(a0.z, h, acc[2]); acc[3] = fmaf(a0.w, h, acc[3]);
    acc[4] = fmaf(a1.x, h, acc[4]); acc[5] = fmaf(a1.y, h, acc[5]);
    acc[6] = fmaf(a1.z, h, acc[6]); acc[7] = fmaf(a1.w, h, acc[7]);
  }
#pragma unroll
  for (int j = 0; j < 8; j++)
    g_H2[(size_t)(ob + j) * M_GRID + m] = fmaxf(acc[j] + b2[ob + j], 0.0f);
}

// ---- k_g3: split-K partials of W3odd·H2.
// Grid (32 m-tiles, 4 k-splits) = 128 blocks. lane = m; wave covers 16 p's.
// A via uniform s_load dx16 from W3T; B coalesced global b32 from g_H2 (L2).
__global__ __launch_bounds__(256) void k_g3() {
  const int t = threadIdx.x;
  const int lane = t & 63;
  const int wave = t >> 6;
  const int m = blockIdx.x * 64 + lane;
  const int s = blockIdx.y;
  const int p0 = wave * 16;
  const int k0 = s * 64;
  float acc[16] = {};
#pragma unroll 4
  for (int k = 0; k < 64; k++) {
    const float b = g_H2[(size_t)(k0 + k) * M_GRID + m];             // coalesced
    const float4* a4 = (const float4*)(g_W3T + (size_t)(k0 + k) * 64 + p0);  // uniform
    const float4 a0 = a4[0], a1 = a4[1], a2 = a4[2], a3 = a4[3];
    acc[0]  = fmaf(a0.x, b, acc[0]);  acc[1]  = fmaf(a0.y, b, acc[1]);
    acc[2]  = fmaf(a0.z, b, acc[2]);  acc[3]  = fmaf(a0.w, b, acc[3]);
    acc[4]  = fmaf(a1.x, b, acc[4]);  acc[5]  = fmaf(a1.y, b, acc[5]);
    acc[6]  = fmaf(a1.z, b, acc[6]);  acc[7]  = fmaf(a1.w, b, acc[7]);
    acc[8]  = fmaf(a2.x, b, acc[8]);  acc[9]  = fmaf(a2.y, b, acc[9]);
    acc[10] = fmaf(a2.z, b, acc[10]); acc[11] = fmaf(a2.w, b, acc[11]);
    acc[12] = fmaf(a3.x, b, acc[12]); acc[13] = fmaf(a3.y, b, acc[13]);
    acc[14] = fmaf(a3.z, b, acc[14]); acc[15] = fmaf(a3.w, b, acc[15]);
  }
#pragma unroll
  for (int j = 0; j < 16; j++)
    g_part[(size_t)(s * 64 + p0 + j) * M_GRID + m] = acc[j];
}

// ---- k_proc: sum the 4 k-split partials + bias -> raws, then process
// columns into g_table (r2's proven path). 32 blocks, 256 threads.
__global__ __launch_bounds__(256) void k_proc(const float* __restrict__ b3) {
  __shared__ float raws[64][65];  // [p][m_local]
  const int t = threadIdx.x;
  const int m0 = blockIdx.x * 64;
  const int p = t >> 2, mseg = (t & 3) * 16;
  const int bi = (p < 63) ? (2 * p + 1) : 1;
  const float bias = b3[bi];
  float v[16];
#pragma unroll
  for (int i = 0; i < 16; i++) v[i] = bias;
#pragma unroll
  for (int s = 0; s < 4; s++) {
    const float* src = g_part + (size_t)(s * 64 + p) * M_GRID + m0 + mseg;
#pragma unroll
    for (int q = 0; q < 4; q++) {
      const float4 a = ((const float4*)src)[q];
      v[4 * q + 0] += a.x; v[4 * q + 1] += a.y;
      v[4 * q + 2] += a.z; v[4 * q + 3] += a.w;
    }
  }
#pragma unroll
  for (int i = 0; i < 16; i++) raws[p][mseg + i] = v[i];
  __syncthreads();
  if (t < 64)
    process_column(&raws[0][t], 65, g_table + (size_t)(m0 + t) * REC);
  if (t == 64 && blockIdx.x == 0)
    process_column(b3, 2, g_knots0);  // dim-0 constant knots
}

// ---------------- Main flow kernel: 4 steps per sample (verbatim round-2)
__global__ __launch_bounds__(256) void k_main(const float* __restrict__ x,
                                              float* __restrict__ out) {
  __shared__ float kn0[REC];
  for (int j = threadIdx.x; j < REC; j += 256) kn0[j] = g_knots0[j];
  __syncthreads();
  const int i = blockIdx.x * 256 + threadIdx.x;
  const float2 xv = ((const float2*)x)[i];
  float z0 = xv.x, z1 = xv.y;
  ((float2*)out)[i] = xv;  // step 0 = input
  for (int t = 0; t < 4; t++) {
    float tt = (z0 - U_LO) * INV_DELTA;
    int i0 = (int)floorf(tt);
    i0 = min(max(i0, 0), M_GRID - 2);
    float f = fminf(fmaxf(tt - (float)i0, 0.0f), 1.0f);
    const float* r0 = g_table + (size_t)i0 * REC;
    const float* r1 = r0 + REC;
    float cwv[17];
#pragma unroll
    for (int q = 0; q < 4; q++) {
      float4 a = *(const float4*)(r0 + 4 * q);
      float4 b = *(const float4*)(r1 + 4 * q);
      cwv[4 * q + 0] = fmaf(f, b.x - a.x, a.x);
      cwv[4 * q + 1] = fmaf(f, b.y - a.y, a.y);
      cwv[4 * q + 2] = fmaf(f, b.z - a.z, a.z);
      cwv[4 * q + 3] = fmaf(f, b.w - a.w, a.w);
    }
    cwv[16] = 5.0f;  // exact in every record
    float xc1 = fminf(fmaxf(z1, -5.0f), 5.0f);
    int k1 = -1;
    float xk = cwv[0], xk1 = cwv[16];
    bool seen = false;
#pragma unroll
    for (int j = 0; j < 16; j++) {
      bool c = xc1 >= cwv[j];
      k1 += c ? 1 : 0;
      xk = c ? cwv[j] : xk;
      bool ff = (!c) && (!seen);
      xk1 = ff ? cwv[j] : xk1;
      seen = seen || (!c);
    }
    const float* s0 = r0 + 20 + 8 * k1;
    const float* s1 = s0 + REC;
    float4 pa = *(const float4*)s0;
    float4 pb = *(const float4*)s1;
    float la = s0[4], lb = s1[4];
    float yk  = fmaf(f, pb.x - pa.x, pa.x);
    float yk1 = fmaf(f, pb.y - pa.y, pa.y);
    float dk  = fmaf(f, pb.z - pa.z, pa.z);
    float dk1 = fmaf(f, pb.w - pa.w, pa.w);
    float lam = fmaf(f, lb - la, la);
    float z1n = spline_eval(z1, xk, xk1, yk, yk1, dk, dk1, lam);
    float xc0 = fminf(fmaxf(z0, -5.0f), 5.0f);
    int k0 = -1;
    float xk0 = kn0[0], xk01 = kn0[16];
    bool seen0 = false;
#pragma unroll
    for (int j = 0; j < 16; j++) {
      float cj = kn0[j];
      bool c = xc0 >= cj;
      k0 += c ? 1 : 0;
      xk0 = c ? cj : xk0;
      bool ff = (!c) && (!seen0);
      xk01 = ff ? cj : xk01;
      seen0 = seen0 || (!c);
    }
    const int sb = 20 + 8 * k0;
    float z0n = spline_eval(z0, xk0, xk01, kn0[sb], kn0[sb + 1],
                            kn0[sb + 2], kn0[sb + 3], kn0[sb + 4]);
    z0 = z0n; z1 = z1n;
    ((float2*)(out + (size_t)(t + 1) * (N_SAMPLES * 2)))[i] = make_float2(z0, z1);
  }
}

extern "C" void kernel_launch(void* const* d_in, const int* in_sizes, int n_in,
                              void* d_out, int out_size, void* d_ws, size_t ws_size,
                              hipStream_t stream) {
  const float* x  = (const float*)d_in[0];
  const float* W1 = (const float*)d_in[1];
  const float* b1 = (const float*)d_in[2];
  const float* W2 = (const float*)d_in[3];
  const float* b2 = (const float*)d_in[4];
  const float* W3 = (const float*)d_in[5];
  const float* b3 = (const float*)d_in[6];
  float* out = (float*)d_out;
  hipLaunchKernelGGL(k_prep, dim3(20), dim3(256), 0, stream, W1, b1, W2, W3);
  hipLaunchKernelGGL(k_g2,   dim3(M_GRID / 64, 8), dim3(256), 0, stream, b2);
  hipLaunchKernelGGL(k_g3,   dim3(M_GRID / 64, 4), dim3(256), 0, stream);
  hipLaunchKernelGGL(k_proc, dim3(M_GRID / 64), dim3(256), 0, stream, b3);
  hipLaunchKernelGGL(k_main, dim3(N_SAMPLES / 256), dim3(256), 0, stream, x, out);
}